// Round 1
// baseline (3023.132 us; speedup 1.0000x reference)
//
#include <hip/hip_runtime.h>

#define D_IN 512
#define D_OUT 256

// ---------------- GEMM: supports = inputs @ W ----------------
// fp32, 64x64 tile, TK=16, 256 threads, 4x4 micro-tile per thread.
#define TM 64
#define TN 64
#define TK 16

__global__ __launch_bounds__(256) void gemm_f32(const float* __restrict__ A,
                                                const float* __restrict__ W,
                                                float* __restrict__ S, int M) {
    __shared__ float As[TK][TM + 1];  // +1 pad: break 16-way bank conflict on store
    __shared__ float Bs[TK][TN];
    const int bm = blockIdx.x * TM;
    const int bn = blockIdx.y * TN;
    const int tid = threadIdx.x;
    const int tx = tid & 15;   // N direction (16 threads)
    const int ty = tid >> 4;   // M direction (16 threads)
    float acc[4][4] = {};

    for (int k0 = 0; k0 < D_IN; k0 += TK) {
        // Load A tile 64x16: idx/16 = m, idx%16 = k (coalesced over k within a row)
#pragma unroll
        for (int i = 0; i < 4; ++i) {
            int idx = tid + i * 256;
            int m = idx >> 4;
            int k = idx & 15;
            int gm = bm + m;
            As[k][m] = (gm < M) ? A[(size_t)gm * D_IN + k0 + k] : 0.f;
        }
        // Load B tile 16x64: idx/64 = k, idx%64 = n (fully coalesced)
#pragma unroll
        for (int i = 0; i < 4; ++i) {
            int idx = tid + i * 256;
            int k = idx >> 6;
            int n = idx & 63;
            Bs[k][n] = W[(size_t)(k0 + k) * D_OUT + bn + n];
        }
        __syncthreads();
#pragma unroll
        for (int k = 0; k < TK; ++k) {
            float a[4], b[4];
#pragma unroll
            for (int i = 0; i < 4; ++i) a[i] = As[k][ty * 4 + i];
#pragma unroll
            for (int j = 0; j < 4; ++j) b[j] = Bs[k][tx * 4 + j];
#pragma unroll
            for (int i = 0; i < 4; ++i)
#pragma unroll
                for (int j = 0; j < 4; ++j) acc[i][j] += a[i] * b[j];
        }
        __syncthreads();
    }
#pragma unroll
    for (int i = 0; i < 4; ++i) {
        int gm = bm + ty * 4 + i;
        if (gm < M) {
#pragma unroll
            for (int j = 0; j < 4; ++j)
                S[(size_t)gm * D_OUT + bn + tx * 4 + j] = acc[i][j];
        }
    }
}

// ---------------- Init: out[i][:] = bias ----------------
// d_out is re-poisoned (0xAA) before every timed launch -> must initialize.
__global__ __launch_bounds__(256) void init_out(float* __restrict__ out,
                                                const float* __restrict__ bias,
                                                int total4) {
    int i = blockIdx.x * blockDim.x + threadIdx.x;
    if (i < total4) {
        const float4* b4 = (const float4*)bias;
        ((float4*)out)[i] = b4[i & (D_OUT / 4 - 1)];  // D_OUT/4 = 64, power of 2
    }
}

// ---------------- SpMM scatter: out[row[e]] += vals[e] * S[col[e]] ----------------
// One wave (64 lanes) per edge; each lane handles 4 consecutive columns (float4).
__global__ __launch_bounds__(256) void spmm_scatter(const float* __restrict__ S,
                                                    const float* __restrict__ vals,
                                                    const int* __restrict__ rows,
                                                    const int* __restrict__ cols,
                                                    float* __restrict__ out, int E) {
    const int e = blockIdx.x * 4 + (threadIdx.x >> 6);
    if (e >= E) return;
    const int lane = threadIdx.x & 63;
    const float v = vals[e];
    const int c = cols[e];
    const int r = rows[e];
    float4 s = ((const float4*)(S + (size_t)c * D_OUT))[lane];
    float* dst = out + (size_t)r * D_OUT + (size_t)lane * 4;
    atomicAdd(dst + 0, s.x * v);
    atomicAdd(dst + 1, s.y * v);
    atomicAdd(dst + 2, s.z * v);
    atomicAdd(dst + 3, s.w * v);
}

extern "C" void kernel_launch(void* const* d_in, const int* in_sizes, int n_in,
                              void* d_out, int out_size, void* d_ws, size_t ws_size,
                              hipStream_t stream) {
    const float* inputs    = (const float*)d_in[0];
    const float* weights   = (const float*)d_in[1];
    const float* bias      = (const float*)d_in[2];
    const float* edge_vals = (const float*)d_in[3];
    const int*   edge_row  = (const int*)d_in[4];
    const int*   edge_col  = (const int*)d_in[5];
    float* out = (float*)d_out;

    const int M = in_sizes[0] / D_IN;  // 50000 nodes
    const int E = in_sizes[3];         // 800000 edges

    float* S = (float*)d_ws;           // supports: M * D_OUT floats = 51.2 MB

    // 1) supports = inputs @ W
    dim3 ggrid((M + TM - 1) / TM, D_OUT / TN);
    gemm_f32<<<ggrid, 256, 0, stream>>>(inputs, weights, S, M);

    // 2) out = broadcast(bias)
    int total4 = M * D_OUT / 4;
    init_out<<<(total4 + 255) / 256, 256, 0, stream>>>(out, bias, total4);

    // 3) scatter-add messages
    spmm_scatter<<<(E + 3) / 4, 256, 0, stream>>>(S, edge_vals, edge_row, edge_col,
                                                  out, E);
}

// Round 2
// 657.965 us; speedup vs baseline: 4.5947x; 4.5947x over previous
//
#include <hip/hip_runtime.h>

#define D_IN 512
#define D_OUT 256

// ---------------- GEMM: supports = inputs @ W ----------------
#define TM 64
#define TN 64
#define TK 16

__global__ __launch_bounds__(256) void gemm_f32(const float* __restrict__ A,
                                                const float* __restrict__ W,
                                                float* __restrict__ S, int M) {
    __shared__ float As[TK][TM + 1];
    __shared__ float Bs[TK][TN];
    const int bm = blockIdx.x * TM;
    const int bn = blockIdx.y * TN;
    const int tid = threadIdx.x;
    const int tx = tid & 15;
    const int ty = tid >> 4;
    float acc[4][4] = {};

    for (int k0 = 0; k0 < D_IN; k0 += TK) {
#pragma unroll
        for (int i = 0; i < 4; ++i) {
            int idx = tid + i * 256;
            int m = idx >> 4;
            int k = idx & 15;
            int gm = bm + m;
            As[k][m] = (gm < M) ? A[(size_t)gm * D_IN + k0 + k] : 0.f;
        }
#pragma unroll
        for (int i = 0; i < 4; ++i) {
            int idx = tid + i * 256;
            int k = idx >> 6;
            int n = idx & 63;
            Bs[k][n] = W[(size_t)(k0 + k) * D_OUT + bn + n];
        }
        __syncthreads();
#pragma unroll
        for (int k = 0; k < TK; ++k) {
            float a[4], b[4];
#pragma unroll
            for (int i = 0; i < 4; ++i) a[i] = As[k][ty * 4 + i];
#pragma unroll
            for (int j = 0; j < 4; ++j) b[j] = Bs[k][tx * 4 + j];
#pragma unroll
            for (int i = 0; i < 4; ++i)
#pragma unroll
                for (int j = 0; j < 4; ++j) acc[i][j] += a[i] * b[j];
        }
        __syncthreads();
    }
#pragma unroll
    for (int i = 0; i < 4; ++i) {
        int gm = bm + ty * 4 + i;
        if (gm < M) {
#pragma unroll
            for (int j = 0; j < 4; ++j)
                S[(size_t)gm * D_OUT + bn + tx * 4 + j] = acc[i][j];
        }
    }
}

// ---------------- CSR build ----------------
__global__ __launch_bounds__(256) void hist_rows(const int* __restrict__ rows,
                                                 int* __restrict__ cnt, int E) {
    int e = blockIdx.x * 256 + threadIdx.x;
    if (e < E) atomicAdd(&cnt[rows[e]], 1);
}

// Exclusive scan of cnt[0..M) -> ptr[0..M], single 1024-thread block.
__global__ __launch_bounds__(1024) void scan_rowptr(const int* __restrict__ cnt,
                                                    int* __restrict__ ptr, int M) {
    __shared__ int buf[1024];
    __shared__ int carry;
    const int t = threadIdx.x;
    if (t == 0) carry = 0;
    __syncthreads();
    for (int base = 0; base < M; base += 1024) {
        int i = base + t;
        int v = (i < M) ? cnt[i] : 0;
        buf[t] = v;
        __syncthreads();
#pragma unroll
        for (int off = 1; off < 1024; off <<= 1) {
            int x = (t >= off) ? buf[t - off] : 0;
            __syncthreads();
            buf[t] += x;
            __syncthreads();
        }
        int incl = buf[t];
        if (i < M) ptr[i] = carry + (incl - v);
        __syncthreads();              // everyone has read carry
        if (t == 0) carry += buf[1023];
        __syncthreads();
    }
    if (t == 0) ptr[M] = carry;
}

// Place each edge's (col, val) payload at its sorted position.
__global__ __launch_bounds__(256) void build_sorted(const float* __restrict__ vals,
                                                    const int* __restrict__ rows,
                                                    const int* __restrict__ cols,
                                                    const int* __restrict__ ptr,
                                                    int* __restrict__ cnt,
                                                    int2* __restrict__ edges, int E) {
    int e = blockIdx.x * 256 + threadIdx.x;
    if (e >= E) return;
    int r = rows[e];
    int pos = ptr[r] + atomicAdd(&cnt[r], 1);
    edges[pos] = make_int2(cols[e], __float_as_int(vals[e]));
}

// ---------------- Aggregate: one wave per row, write once ----------------
__global__ __launch_bounds__(256) void spmm_rows(const float* __restrict__ S,
                                                 const int2* __restrict__ edges,
                                                 const int* __restrict__ ptr,
                                                 const float* __restrict__ bias,
                                                 float* __restrict__ out, int M) {
    const int row = blockIdx.x * 4 + (threadIdx.x >> 6);
    if (row >= M) return;
    const int lane = threadIdx.x & 63;
    float4 acc = ((const float4*)bias)[lane];
    const int beg = ptr[row];
    const int end = ptr[row + 1];
    for (int j = beg; j < end; ++j) {
        int2 e = edges[j];                 // wave-uniform load (broadcast)
        float v = __int_as_float(e.y);
        float4 s = ((const float4*)S)[(size_t)e.x * 64 + lane];
        acc.x += v * s.x;
        acc.y += v * s.y;
        acc.z += v * s.z;
        acc.w += v * s.w;
    }
    ((float4*)out)[(size_t)row * 64 + lane] = acc;
}

extern "C" void kernel_launch(void* const* d_in, const int* in_sizes, int n_in,
                              void* d_out, int out_size, void* d_ws, size_t ws_size,
                              hipStream_t stream) {
    const float* inputs    = (const float*)d_in[0];
    const float* weights   = (const float*)d_in[1];
    const float* bias      = (const float*)d_in[2];
    const float* edge_vals = (const float*)d_in[3];
    const int*   edge_row  = (const int*)d_in[4];
    const int*   edge_col  = (const int*)d_in[5];
    float* out = (float*)d_out;

    const int M = in_sizes[0] / D_IN;  // 50000
    const int E = in_sizes[3];         // 800000

    // Workspace layout (all offsets 8B-aligned):
    //   S:      M*D_OUT floats            (51,200,000 B)
    //   edges:  E int2                    ( 6,400,000 B)
    //   ptr:    M+1 ints
    //   cnt:    M ints
    char* ws = (char*)d_ws;
    float* S     = (float*)ws;
    int2*  edges = (int2*)(ws + (size_t)M * D_OUT * 4);
    int*   ptr   = (int*)((char*)edges + (size_t)E * 8);
    int*   cnt   = ptr + (M + 1);

    // 1) supports = inputs @ W
    dim3 ggrid((M + TM - 1) / TM, D_OUT / TN);
    gemm_f32<<<ggrid, 256, 0, stream>>>(inputs, weights, S, M);

    // 2) CSR build: histogram -> scan -> stable place
    hipMemsetAsync(cnt, 0, (size_t)M * 4, stream);
    hist_rows<<<(E + 255) / 256, 256, 0, stream>>>(edge_row, cnt, E);
    scan_rowptr<<<1, 1024, 0, stream>>>(cnt, ptr, M);
    hipMemsetAsync(cnt, 0, (size_t)M * 4, stream);
    build_sorted<<<(E + 255) / 256, 256, 0, stream>>>(edge_vals, edge_row, edge_col,
                                                      ptr, cnt, edges, E);

    // 3) aggregate: one wave per row, single write per output element
    spmm_rows<<<(M + 3) / 4, 256, 0, stream>>>(S, edges, ptr, bias, out, M);
}

// Round 3
// 421.747 us; speedup vs baseline: 7.1681x; 1.5601x over previous
//
#include <hip/hip_runtime.h>

#define D_IN 512
#define D_OUT 256
#define BM 128
#define BN 128
#define BK 32
#define LDK 40   // padded LDS row stride in elems: 80 B = 20 banks -> 2-way (free)

typedef short short8 __attribute__((ext_vector_type(8)));
typedef float floatx4 __attribute__((ext_vector_type(4)));

// fp32 -> bf16 round-to-nearest-even
static __device__ __forceinline__ unsigned short f2bf(float f) {
    unsigned u = __float_as_uint(f);
    u += 0x7FFF + ((u >> 16) & 1);
    return (unsigned short)(u >> 16);
}
static __device__ __forceinline__ float bf2f(unsigned short h) {
    return __uint_as_float((unsigned)h << 16);
}

// ---------------- W convert+transpose: Wt[n][k] = bf16(W[k][n]) ----------------
__global__ __launch_bounds__(256) void convert_w(const float* __restrict__ W,
                                                 unsigned short* __restrict__ Wt) {
    int t = blockIdx.x * 256 + threadIdx.x;   // t in [0, 256*512)
    int n = t >> 9;
    int k = t & 511;
    Wt[t] = f2bf(W[(size_t)k * D_OUT + n]);   // writes contiguous; reads L2-cached
}

// ---------------- GEMM: S(bf16) = bf16(A) @ bf16(W), fp32 accum ----------------
__global__ __launch_bounds__(256) void gemm_bf16(const float* __restrict__ A,
                                                 const unsigned short* __restrict__ Wt,
                                                 unsigned short* __restrict__ S, int M) {
    __shared__ unsigned short As[BM * LDK];
    __shared__ unsigned short Bs[BN * LDK];
    const int tid  = threadIdx.x;
    const int lane = tid & 63;
    const int wave = tid >> 6;
    const int wm   = (wave >> 1) * 64;   // wave's M offset in tile
    const int wn   = (wave & 1) * 64;    // wave's N offset in tile
    const int bm   = blockIdx.x * BM;
    const int bn   = blockIdx.y * BN;
    const int l15  = lane & 15;
    const int quad = lane >> 4;

    floatx4 acc[4][4] = {};

    for (int k0 = 0; k0 < D_IN; k0 += BK) {
        // stage A: 128 rows x 32 k, fp32 float4 load -> bf16 ushort4 LDS write
#pragma unroll
        for (int i = 0; i < 4; ++i) {
            int item = tid + i * 256;        // 0..1023
            int m  = item >> 3;
            int k4 = (item & 7) * 4;
            int gm = bm + m;
            float4 a = (gm < M) ? *(const float4*)(A + (size_t)gm * D_IN + k0 + k4)
                                : make_float4(0.f, 0.f, 0.f, 0.f);
            ushort4 b;
            b.x = f2bf(a.x); b.y = f2bf(a.y); b.z = f2bf(a.z); b.w = f2bf(a.w);
            *(ushort4*)(As + m * LDK + k4) = b;
        }
        // stage B: Bs[n][k] = Wt[bn+n][k0+k]  (already bf16, K-contiguous)
#pragma unroll
        for (int i = 0; i < 4; ++i) {
            int item = tid + i * 256;
            int n  = item >> 3;
            int k4 = (item & 7) * 4;
            *(ushort4*)(Bs + n * LDK + k4) =
                *(const ushort4*)(Wt + (size_t)(bn + n) * D_IN + k0 + k4);
        }
        __syncthreads();

        // fragments: A[m=l15][k=quad*8+j], B[n=l15][k=quad*8+j]
        short8 af[4], bf[4];
#pragma unroll
        for (int i = 0; i < 4; ++i)
            af[i] = *(const short8*)(As + (wm + i * 16 + l15) * LDK + quad * 8);
#pragma unroll
        for (int j = 0; j < 4; ++j)
            bf[j] = *(const short8*)(Bs + (wn + j * 16 + l15) * LDK + quad * 8);
#pragma unroll
        for (int i = 0; i < 4; ++i)
#pragma unroll
            for (int j = 0; j < 4; ++j)
                acc[i][j] = __builtin_amdgcn_mfma_f32_16x16x32_bf16(
                    af[i], bf[j], acc[i][j], 0, 0, 0);
        __syncthreads();
    }

    // epilogue: C row = wm+i*16+quad*4+r, col = wn+j*16+l15
#pragma unroll
    for (int i = 0; i < 4; ++i) {
#pragma unroll
        for (int r = 0; r < 4; ++r) {
            int gm = bm + wm + i * 16 + quad * 4 + r;
            if (gm < M) {
#pragma unroll
                for (int j = 0; j < 4; ++j)
                    S[(size_t)gm * D_OUT + bn + wn + j * 16 + l15] = f2bf(acc[i][j][r]);
            }
        }
    }
}

// ---------------- CSR build ----------------
__global__ __launch_bounds__(256) void hist_rows(const int* __restrict__ rows,
                                                 int* __restrict__ cnt, int E) {
    int e = blockIdx.x * 256 + threadIdx.x;
    if (e < E) atomicAdd(&cnt[rows[e]], 1);
}

// Exclusive scan of cnt[0..M) -> ptr[0..M], single block, shfl-based.
__global__ __launch_bounds__(1024) void scan_rowptr(const int* __restrict__ cnt,
                                                    int* __restrict__ ptr, int M) {
    __shared__ int wsum[16];
    __shared__ int sh_carry, sh_total;
    const int t = threadIdx.x;
    const int lane = t & 63, wave = t >> 6;
    if (t == 0) sh_carry = 0;
    __syncthreads();
    for (int base = 0; base < M; base += 1024) {
        int i = base + t;
        int v = (i < M) ? cnt[i] : 0;
        int incl = v;
#pragma unroll
        for (int off = 1; off < 64; off <<= 1) {
            int x = __shfl_up(incl, off, 64);
            if (lane >= off) incl += x;
        }
        if (lane == 63) wsum[wave] = incl;
        __syncthreads();
        if (t == 0) {
            int s = 0;
#pragma unroll
            for (int w = 0; w < 16; ++w) { int x = wsum[w]; wsum[w] = s; s += x; }
            sh_total = s;
        }
        __syncthreads();
        int carry = sh_carry;
        if (i < M) ptr[i] = carry + wsum[wave] + (incl - v);
        __syncthreads();
        if (t == 0) sh_carry = carry + sh_total;
        __syncthreads();
    }
    if (t == 0) ptr[M] = sh_carry;
}

__global__ __launch_bounds__(256) void build_sorted(const float* __restrict__ vals,
                                                    const int* __restrict__ rows,
                                                    const int* __restrict__ cols,
                                                    const int* __restrict__ ptr,
                                                    int* __restrict__ cnt,
                                                    int2* __restrict__ edges, int E) {
    int e = blockIdx.x * 256 + threadIdx.x;
    if (e >= E) return;
    int r = rows[e];
    int pos = ptr[r] + atomicAdd(&cnt[r], 1);
    edges[pos] = make_int2(cols[e], __float_as_int(vals[e]));
}

// ---------------- Aggregate: one wave per row, bf16 gather, fp32 accum ----------------
__global__ __launch_bounds__(256) void spmm_rows(const unsigned short* __restrict__ S,
                                                 const int2* __restrict__ edges,
                                                 const int* __restrict__ ptr,
                                                 const float* __restrict__ bias,
                                                 float* __restrict__ out, int M) {
    const int row = blockIdx.x * 4 + (threadIdx.x >> 6);
    if (row >= M) return;
    const int lane = threadIdx.x & 63;
    float4 acc = ((const float4*)bias)[lane];
    const int beg = ptr[row];
    const int end = ptr[row + 1];
    int j = beg;
    for (; j + 1 < end; j += 2) {   // 2-edge unroll: two independent gathers in flight
        int2 e0 = edges[j];
        int2 e1 = edges[j + 1];
        float v0 = __int_as_float(e0.y);
        float v1 = __int_as_float(e1.y);
        ushort4 s0 = ((const ushort4*)(S + (size_t)e0.x * D_OUT))[lane];
        ushort4 s1 = ((const ushort4*)(S + (size_t)e1.x * D_OUT))[lane];
        acc.x += v0 * bf2f(s0.x) + v1 * bf2f(s1.x);
        acc.y += v0 * bf2f(s0.y) + v1 * bf2f(s1.y);
        acc.z += v0 * bf2f(s0.z) + v1 * bf2f(s1.z);
        acc.w += v0 * bf2f(s0.w) + v1 * bf2f(s1.w);
    }
    if (j < end) {
        int2 e = edges[j];
        float v = __int_as_float(e.y);
        ushort4 s = ((const ushort4*)(S + (size_t)e.x * D_OUT))[lane];
        acc.x += v * bf2f(s.x);
        acc.y += v * bf2f(s.y);
        acc.z += v * bf2f(s.z);
        acc.w += v * bf2f(s.w);
    }
    ((float4*)out)[(size_t)row * 64 + lane] = acc;
}

extern "C" void kernel_launch(void* const* d_in, const int* in_sizes, int n_in,
                              void* d_out, int out_size, void* d_ws, size_t ws_size,
                              hipStream_t stream) {
    const float* inputs    = (const float*)d_in[0];
    const float* weights   = (const float*)d_in[1];
    const float* bias      = (const float*)d_in[2];
    const float* edge_vals = (const float*)d_in[3];
    const int*   edge_row  = (const int*)d_in[4];
    const int*   edge_col  = (const int*)d_in[5];
    float* out = (float*)d_out;

    const int M = in_sizes[0] / D_IN;  // 50000
    const int E = in_sizes[3];         // 800000

    // Workspace layout (16B-aligned chunks):
    //   S:     M*D_OUT bf16   (25.6 MB)
    //   Wt:    D_OUT*D_IN bf16 (256 KB, transposed)
    //   edges: E int2          (6.4 MB)
    //   ptr:   M+1 ints; cnt: M ints
    char* ws = (char*)d_ws;
    unsigned short* S  = (unsigned short*)ws;
    unsigned short* Wt = (unsigned short*)(ws + (size_t)M * D_OUT * 2);
    int2* edges        = (int2*)((char*)Wt + (size_t)D_OUT * D_IN * 2);
    int*  ptr          = (int*)((char*)edges + (size_t)E * 8);
    int*  cnt          = ptr + (M + 1);

    // 1) W -> bf16 transposed
    convert_w<<<(D_IN * D_OUT) / 256, 256, 0, stream>>>(weights, Wt);

    // 2) supports = inputs @ W  (bf16 MFMA, fused A conversion)
    dim3 ggrid((M + BM - 1) / BM, D_OUT / BN);
    gemm_bf16<<<ggrid, 256, 0, stream>>>(inputs, Wt, S, M);

    // 3) CSR build
    hipMemsetAsync(cnt, 0, (size_t)M * 4, stream);
    hist_rows<<<(E + 255) / 256, 256, 0, stream>>>(edge_row, cnt, E);
    scan_rowptr<<<1, 1024, 0, stream>>>(cnt, ptr, M);
    hipMemsetAsync(cnt, 0, (size_t)M * 4, stream);
    build_sorted<<<(E + 255) / 256, 256, 0, stream>>>(edge_vals, edge_row, edge_col,
                                                      ptr, cnt, edges, E);

    // 4) aggregate
    spmm_rows<<<(M + 3) / 4, 256, 0, stream>>>(S, edges, ptr, bias, out, M);
}

// Round 4
// 334.895 us; speedup vs baseline: 9.0271x; 1.2593x over previous
//
#include <hip/hip_runtime.h>

#define D_IN 512
#define D_OUT 256
#define BM 128
#define BN 128
#define BK 32
#define LDK 40   // padded LDS row stride (elems): 80 B, 16B-aligned rows, 2-way bank alias

typedef short short8 __attribute__((ext_vector_type(8)));
typedef float floatx4 __attribute__((ext_vector_type(4)));

static __device__ __forceinline__ unsigned short f2bf(float f) {
    unsigned u = __float_as_uint(f);
    u += 0x7FFF + ((u >> 16) & 1);
    return (unsigned short)(u >> 16);
}
static __device__ __forceinline__ float bf2f(unsigned short h) {
    return __uint_as_float((unsigned)h << 16);
}

// ---------------- W convert+transpose: Wt[n][k] = bf16(W[k][n]) ----------------
__global__ __launch_bounds__(256) void convert_w(const float* __restrict__ W,
                                                 unsigned short* __restrict__ Wt) {
    int t = blockIdx.x * 256 + threadIdx.x;
    int n = t >> 9;
    int k = t & 511;
    Wt[t] = f2bf(W[(size_t)k * D_OUT + n]);
}

// ---------------- GEMM: S(bf16) = bf16(A) @ bf16(W), fp32 accum ----------------
// 512 threads = 8 waves (2 M-groups x 4 N-groups, wave tile 64x32).
// Register-prefetch pipeline: next K-tile's loads issued before MFMA section.
__global__ __launch_bounds__(512) void gemm_bf16(const float* __restrict__ A,
                                                 const unsigned short* __restrict__ Wt,
                                                 unsigned short* __restrict__ S, int M) {
    __shared__ unsigned short As[BM * LDK];
    __shared__ unsigned short Bs[BN * LDK];
    const int tid  = threadIdx.x;
    const int lane = tid & 63;
    const int wave = tid >> 6;
    const int wm   = (wave >> 2) * 64;
    const int wn   = (wave & 3) * 32;
    const int bm   = blockIdx.x * BM;
    const int bn   = blockIdx.y * BN;
    const int l15  = lane & 15;
    const int quad = lane >> 4;

    // staging descriptors: 2 items/thread, item covers 4 consecutive k elems
    const float* aptr[2];
    const unsigned short* bptr[2];
    int aoff[2], boff[2];
    bool aval[2];
#pragma unroll
    for (int i = 0; i < 2; ++i) {
        int item = tid + i * 512;          // 0..1023
        int m  = item >> 3;                // 0..127 (row for A, col for Wt)
        int k4 = (item & 7) * 4;           // 0..28
        int gm = bm + m;
        aval[i] = gm < M;
        aptr[i] = A + (size_t)(aval[i] ? gm : 0) * D_IN + k4;
        aoff[i] = m * LDK + k4;
        bptr[i] = Wt + (size_t)(bn + m) * D_IN + k4;
        boff[i] = m * LDK + k4;
    }

    // prologue: load k0 = 0 tile into registers
    float4  aR[2];
    ushort4 bR[2];
#pragma unroll
    for (int i = 0; i < 2; ++i) {
        aR[i] = aval[i] ? *(const float4*)(aptr[i]) : make_float4(0.f, 0.f, 0.f, 0.f);
        bR[i] = *(const ushort4*)(bptr[i]);
    }

    floatx4 acc[4][2] = {};

    for (int k0 = 0; k0 < D_IN; k0 += BK) {
        // drain staged regs -> LDS (A converted to bf16)
#pragma unroll
        for (int i = 0; i < 2; ++i) {
            ushort4 b;
            b.x = f2bf(aR[i].x); b.y = f2bf(aR[i].y);
            b.z = f2bf(aR[i].z); b.w = f2bf(aR[i].w);
            *(ushort4*)(As + aoff[i]) = b;
            *(ushort4*)(Bs + boff[i]) = bR[i];
        }
        __syncthreads();

        // prefetch next K-tile (overlaps with frag reads + MFMA + end barrier)
        if (k0 + BK < D_IN) {
#pragma unroll
            for (int i = 0; i < 2; ++i) {
                aR[i] = aval[i] ? *(const float4*)(aptr[i] + k0 + BK)
                                : make_float4(0.f, 0.f, 0.f, 0.f);
                bR[i] = *(const ushort4*)(bptr[i] + k0 + BK);
            }
        }

        short8 af[4], bfr[2];
#pragma unroll
        for (int i = 0; i < 4; ++i)
            af[i] = *(const short8*)(As + (wm + i * 16 + l15) * LDK + quad * 8);
#pragma unroll
        for (int j = 0; j < 2; ++j)
            bfr[j] = *(const short8*)(Bs + (wn + j * 16 + l15) * LDK + quad * 8);
#pragma unroll
        for (int i = 0; i < 4; ++i)
#pragma unroll
            for (int j = 0; j < 2; ++j)
                acc[i][j] = __builtin_amdgcn_mfma_f32_16x16x32_bf16(
                    af[i], bfr[j], acc[i][j], 0, 0, 0);
        __syncthreads();
    }

    // epilogue: row = wm+i*16+quad*4+r, col = wn+j*16+l15
#pragma unroll
    for (int i = 0; i < 4; ++i) {
#pragma unroll
        for (int r = 0; r < 4; ++r) {
            int gm = bm + wm + i * 16 + quad * 4 + r;
            if (gm < M) {
#pragma unroll
                for (int j = 0; j < 2; ++j)
                    S[(size_t)gm * D_OUT + bn + wn + j * 16 + l15] = f2bf(acc[i][j][r]);
            }
        }
    }
}

// ---------------- CSR build ----------------
__global__ __launch_bounds__(256) void hist_rows(const int* __restrict__ rows,
                                                 int* __restrict__ cnt, int E) {
    int e = blockIdx.x * 256 + threadIdx.x;
    if (e < E) atomicAdd(&cnt[rows[e]], 1);
}

// Phase A: per-block exclusive scan of 4096 elems; block total -> partials[blk]
#define SCAN_B 4096
__global__ __launch_bounds__(1024) void scan_blocks(const int* __restrict__ cnt,
                                                    int* __restrict__ ptr,
                                                    int* __restrict__ partials, int M) {
    __shared__ int wsum[16];
    const int t = threadIdx.x, lane = t & 63, wave = t >> 6;
    const int base = blockIdx.x * SCAN_B + t * 4;
    int4 v = make_int4(0, 0, 0, 0);
    if (base + 3 < M) v = *(const int4*)(cnt + base);
    else {
        if (base + 0 < M) v.x = cnt[base + 0];
        if (base + 1 < M) v.y = cnt[base + 1];
        if (base + 2 < M) v.z = cnt[base + 2];
        if (base + 3 < M) v.w = cnt[base + 3];
    }
    int s = v.x + v.y + v.z + v.w;
    int incl = s;
#pragma unroll
    for (int off = 1; off < 64; off <<= 1) {
        int x = __shfl_up(incl, off, 64);
        if (lane >= off) incl += x;
    }
    if (lane == 63) wsum[wave] = incl;
    __syncthreads();
    if (t == 0) {
        int run = 0;
#pragma unroll
        for (int w = 0; w < 16; ++w) { int x = wsum[w]; wsum[w] = run; run += x; }
        partials[blockIdx.x] = run;
    }
    __syncthreads();
    int e0 = wsum[wave] + (incl - s);
    int e1 = e0 + v.x, e2 = e1 + v.y, e3 = e2 + v.z;
    if (base + 3 < M) *(int4*)(ptr + base) = make_int4(e0, e1, e2, e3);
    else {
        if (base + 0 < M) ptr[base + 0] = e0;
        if (base + 1 < M) ptr[base + 1] = e1;
        if (base + 2 < M) ptr[base + 2] = e2;
        if (base + 3 < M) ptr[base + 3] = e3;
    }
}

// Phase B: exclusive scan of <=64 block partials in one wave; ptr[M] = total
__global__ __launch_bounds__(64) void scan_partials(int* __restrict__ partials,
                                                    int* __restrict__ ptr, int M, int nb) {
    const int t = threadIdx.x;
    int v = (t < nb) ? partials[t] : 0;
    int incl = v;
#pragma unroll
    for (int off = 1; off < 64; off <<= 1) {
        int x = __shfl_up(incl, off, 64);
        if (t >= off) incl += x;
    }
    if (t < nb) partials[t] = incl - v;
    if (t == 63) ptr[M] = incl;
}

// Phase C: add block offsets
__global__ __launch_bounds__(256) void add_offsets(int* __restrict__ ptr,
                                                   const int* __restrict__ partials,
                                                   int M) {
    int i = blockIdx.x * 256 + threadIdx.x;
    if (i < M) ptr[i] += partials[i >> 12];   // SCAN_B = 4096 = 1<<12
}

__global__ __launch_bounds__(256) void build_sorted(const float* __restrict__ vals,
                                                    const int* __restrict__ rows,
                                                    const int* __restrict__ cols,
                                                    const int* __restrict__ ptr,
                                                    int* __restrict__ cnt,
                                                    int2* __restrict__ edges, int E) {
    int e = blockIdx.x * 256 + threadIdx.x;
    if (e >= E) return;
    int r = rows[e];
    int pos = ptr[r] + atomicAdd(&cnt[r], 1);
    edges[pos] = make_int2(cols[e], __float_as_int(vals[e]));
}

// ---------------- Aggregate: one wave/row, 4-edge unroll, fp32 accum ----------------
__global__ __launch_bounds__(256) void spmm_rows(const unsigned short* __restrict__ S,
                                                 const int2* __restrict__ edges,
                                                 const int* __restrict__ ptr,
                                                 const float* __restrict__ bias,
                                                 float* __restrict__ out, int M) {
    const int row = blockIdx.x * 4 + (threadIdx.x >> 6);
    if (row >= M) return;
    const int lane = threadIdx.x & 63;
    float4 a0 = ((const float4*)bias)[lane];
    float4 a1 = make_float4(0.f, 0.f, 0.f, 0.f);
    const int beg = ptr[row];
    const int end = ptr[row + 1];
    int j = beg;
    for (; j + 3 < end; j += 4) {
        int2 e0 = edges[j], e1 = edges[j + 1], e2 = edges[j + 2], e3 = edges[j + 3];
        ushort4 s0 = ((const ushort4*)(S + (size_t)e0.x * D_OUT))[lane];
        ushort4 s1 = ((const ushort4*)(S + (size_t)e1.x * D_OUT))[lane];
        ushort4 s2 = ((const ushort4*)(S + (size_t)e2.x * D_OUT))[lane];
        ushort4 s3 = ((const ushort4*)(S + (size_t)e3.x * D_OUT))[lane];
        float v0 = __int_as_float(e0.y), v1 = __int_as_float(e1.y);
        float v2 = __int_as_float(e2.y), v3 = __int_as_float(e3.y);
        a0.x += v0 * bf2f(s0.x) + v2 * bf2f(s2.x);
        a0.y += v0 * bf2f(s0.y) + v2 * bf2f(s2.y);
        a0.z += v0 * bf2f(s0.z) + v2 * bf2f(s2.z);
        a0.w += v0 * bf2f(s0.w) + v2 * bf2f(s2.w);
        a1.x += v1 * bf2f(s1.x) + v3 * bf2f(s3.x);
        a1.y += v1 * bf2f(s1.y) + v3 * bf2f(s3.y);
        a1.z += v1 * bf2f(s1.z) + v3 * bf2f(s3.z);
        a1.w += v1 * bf2f(s1.w) + v3 * bf2f(s3.w);
    }
    for (; j < end; ++j) {
        int2 e = edges[j];
        float v = __int_as_float(e.y);
        ushort4 s = ((const ushort4*)(S + (size_t)e.x * D_OUT))[lane];
        a0.x += v * bf2f(s.x);
        a0.y += v * bf2f(s.y);
        a0.z += v * bf2f(s.z);
        a0.w += v * bf2f(s.w);
    }
    a0.x += a1.x; a0.y += a1.y; a0.z += a1.z; a0.w += a1.w;
    ((float4*)out)[(size_t)row * 64 + lane] = a0;
}

extern "C" void kernel_launch(void* const* d_in, const int* in_sizes, int n_in,
                              void* d_out, int out_size, void* d_ws, size_t ws_size,
                              hipStream_t stream) {
    const float* inputs    = (const float*)d_in[0];
    const float* weights   = (const float*)d_in[1];
    const float* bias      = (const float*)d_in[2];
    const float* edge_vals = (const float*)d_in[3];
    const int*   edge_row  = (const int*)d_in[4];
    const int*   edge_col  = (const int*)d_in[5];
    float* out = (float*)d_out;

    const int M = in_sizes[0] / D_IN;  // 50000
    const int E = in_sizes[3];         // 800000

    // Workspace (all chunk sizes multiples of 16 B):
    //   S:     M*D_OUT bf16   (25.6 MB)
    //   Wt:    D_OUT*D_IN bf16 (512 KB... actually 256 KB)
    //   edges: E int2          (6.4 MB)
    //   ptr:   M+1 ints (padded to mult of 4), cnt: M ints, partials: 64 ints
    char* ws = (char*)d_ws;
    unsigned short* S  = (unsigned short*)ws;
    unsigned short* Wt = (unsigned short*)(ws + (size_t)M * D_OUT * 2);
    int2* edges        = (int2*)((char*)Wt + (size_t)D_OUT * D_IN * 2);
    int*  ptr          = (int*)((char*)edges + (size_t)E * 8);
    int*  cnt          = ptr + ((M + 4) & ~3);   // keep 16B alignment
    int*  partials     = cnt + M;

    // 1) W -> bf16 transposed
    convert_w<<<(D_IN * D_OUT) / 256, 256, 0, stream>>>(weights, Wt);

    // 2) supports = inputs @ W  (bf16 MFMA, pipelined)
    dim3 ggrid((M + BM - 1) / BM, D_OUT / BN);
    gemm_bf16<<<ggrid, 512, 0, stream>>>(inputs, Wt, S, M);

    // 3) CSR build: histogram -> 3-phase scan -> stable place
    hipMemsetAsync(cnt, 0, (size_t)M * 4, stream);
    hist_rows<<<(E + 255) / 256, 256, 0, stream>>>(edge_row, cnt, E);
    int nb = (M + SCAN_B - 1) / SCAN_B;   // 13
    scan_blocks<<<nb, 1024, 0, stream>>>(cnt, ptr, partials, M);
    scan_partials<<<1, 64, 0, stream>>>(partials, ptr, M, nb);
    add_offsets<<<(M + 255) / 256, 256, 0, stream>>>(ptr, partials, M);
    hipMemsetAsync(cnt, 0, (size_t)M * 4, stream);
    build_sorted<<<(E + 255) / 256, 256, 0, stream>>>(edge_vals, edge_row, edge_col,
                                                      ptr, cnt, edges, E);

    // 4) aggregate
    spmm_rows<<<(M + 3) / 4, 256, 0, stream>>>(S, edges, ptr, bias, out, M);
}